// Round 20
// baseline (236.720 us; speedup 1.0000x reference)
//
#include <hip/hip_runtime.h>

#define D 64
#define NREL 3
#define SRC_MASK 0x1FFFF      // 17 bits: N=100000 < 2^17
#define ATHR 512
#define APT 8
#define ABLK (ATHR * APT)     // 4096 edges per block (bhist, binA)
#define BSH 9                 // 512-node buckets
#define BSZ 512

typedef unsigned short bf16_t;
typedef __attribute__((ext_vector_type(8))) short short8v;   // 8 bf16 = 4 VGPRs
typedef __attribute__((ext_vector_type(4))) float float4v;

__device__ __forceinline__ float bf2f(unsigned int u16) {
  return __uint_as_float(u16 << 16);
}
__device__ __forceinline__ unsigned int f2bf(float f) {
  unsigned int x = __float_as_uint(f);
  return (x + 0x7fffu + ((x >> 16) & 1u)) >> 16;  // round-to-nearest-even
}

// ---------------- tiny zero ----------------
__global__ __launch_bounds__(512) void zero_kernel(int* __restrict__ a,
                                                   int* __restrict__ b, int n) {
  const int t = threadIdx.x;
  for (int i = t; i < n; i += 512) { a[i] = 0; b[i] = 0; }
}

// ---------------- f32 -> bf16 convert (layer-1 input) ----------------
__global__ __launch_bounds__(256) void conv_kernel(
    const float* __restrict__ in, bf16_t* __restrict__ out, int n4) {
  const int i = blockIdx.x * 256 + threadIdx.x;
  if (i >= n4) return;
  const float4 f = reinterpret_cast<const float4*>(in)[i];
  uint2 o;
  o.x = f2bf(f.x) | (f2bf(f.y) << 16);
  o.y = f2bf(f.z) | (f2bf(f.w) << 16);
  reinterpret_cast<uint2*>(out)[i] = o;
}

// ---------------- CSR build (bucket-level only) ----------------
__global__ __launch_bounds__(ATHR) void bhist_kernel(
    const int* __restrict__ dst, int* __restrict__ bdeg, int n_edges, int nb) {
  __shared__ int cnt[200];
  const int t = threadIdx.x;
  for (int b = t; b < nb; b += ATHR) cnt[b] = 0;
  __syncthreads();
  const long e0 = (long)blockIdx.x * ABLK;
#pragma unroll
  for (int i = 0; i < APT; ++i) {
    const long e = e0 + t + (long)i * ATHR;
    if (e < n_edges) atomicAdd(&cnt[dst[e] >> BSH], 1);
  }
  __syncthreads();
  for (int b = t; b < nb; b += ATHR)
    if (cnt[b]) atomicAdd(&bdeg[b], cnt[b]);
}

__global__ __launch_bounds__(512) void bscan_kernel(
    const int* __restrict__ bdeg, int* __restrict__ boffs, int nb) {
  __shared__ int s[512];
  const int t = threadIdx.x;
  const int v = (t < nb) ? bdeg[t] : 0;
  s[t] = v;
  __syncthreads();
  for (int off = 1; off < 512; off <<= 1) {
    const int add = (t >= off) ? s[t - off] : 0;
    __syncthreads();
    s[t] += add;
    __syncthreads();
  }
  if (t < nb) boffs[t] = s[t] - v;
  if (t == 511) boffs[nb] = s[nb - 1];
}

// Phase A (R19-verified staged-flush version).
__global__ __launch_bounds__(ATHR) void binA_kernel(
    const int* __restrict__ src, const int* __restrict__ dst,
    const int* __restrict__ rel, const float* __restrict__ norm,
    const int* __restrict__ boffs, int* __restrict__ bcur,
    int2* __restrict__ binpay, int n_edges, int nb) {
  __shared__ int cnt[256];
  __shared__ int incl[256];
  __shared__ int gbase[200];
  __shared__ int2 staged[ABLK];
  __shared__ unsigned char sbk[ABLK];
  const int t = threadIdx.x;
  const long e0 = (long)blockIdx.x * ABLK;

  for (int b = t; b < 256; b += ATHR) cnt[b] = 0;
  __syncthreads();

  int2 pay[APT];
  int bk[APT], slot[APT];
#pragma unroll
  for (int i = 0; i < APT; ++i) {
    const long e = e0 + t + (long)i * ATHR;
    if (e < n_edges) {
      const int d = dst[e];
      bk[i] = d >> BSH;
      pay[i] = make_int2(src[e] | (rel[e] << 17) | ((d & (BSZ - 1)) << 19),
                         __float_as_int(norm[e]));
      slot[i] = atomicAdd(&cnt[bk[i]], 1);
    } else {
      bk[i] = -1;
    }
  }
  __syncthreads();

  if (t < 256) incl[t] = cnt[t];
  __syncthreads();
  for (int off = 1; off < 256; off <<= 1) {
    int add = 0;
    if (t < 256 && t >= off) add = incl[t - off];
    __syncthreads();
    if (t < 256) incl[t] += add;
    __syncthreads();
  }

  for (int b = t; b < nb; b += ATHR) {
    const int c = cnt[b];
    gbase[b] = c ? (boffs[b] + atomicAdd(&bcur[b], c)) : 0;
  }
  __syncthreads();

#pragma unroll
  for (int i = 0; i < APT; ++i) {
    if (bk[i] >= 0) {
      const int pos = incl[bk[i]] - cnt[bk[i]] + slot[i];
      staged[pos] = pay[i];
      sbk[pos] = (unsigned char)bk[i];
    }
  }
  __syncthreads();

  const int nv = (int)min((long)ABLK, (long)(n_edges - e0));
  for (int j = t; j < nv; j += ATHR) {
    const int b = sbk[j];
    const int excl = incl[b] - cnt[b];
    binpay[gbase[b] + j - excl] = staged[j];
  }
}

// Phase B: one 512-thread block per 512-node bucket (R16-verified).
__global__ __launch_bounds__(512) void binB_kernel(
    const int2* __restrict__ binpay, const int* __restrict__ boffs,
    int2* __restrict__ edgebuf, int* __restrict__ deg, int* __restrict__ offs,
    int n_nodes) {
  __shared__ int cnt[512];
  __shared__ int ss[512];
  __shared__ int cur[512];
  const int b = blockIdx.x;
  const int t = threadIdx.x;
  cnt[t] = 0;
  __syncthreads();
  const int start = boffs[b];
  const int end = boffs[b + 1];
  for (int i = start + t; i < end; i += 512)
    atomicAdd(&cnt[((unsigned)binpay[i].x >> 19) & (BSZ - 1)], 1);
  __syncthreads();
  const int v = cnt[t];
  ss[t] = v;
  __syncthreads();
  for (int off = 1; off < 512; off <<= 1) {
    const int add = (t >= off) ? ss[t - off] : 0;
    __syncthreads();
    ss[t] += add;
    __syncthreads();
  }
  const int excl = ss[t] - v;
  cur[t] = excl;
  const int node = (b << BSH) + t;
  if (node < n_nodes) {
    deg[node] = v;
    offs[node] = start + excl;
  }
  __syncthreads();
  for (int i = start + t; i < end; i += 512) {
    const int2 pay = binpay[i];
    const int dl = ((unsigned)pay.x >> 19) & (BSZ - 1);
    const int pos = start + atomicAdd(&cur[dl], 1);
    edgebuf[pos] = pay;
  }
}

// ---------------- aggregate-first gather: agg_r[n] = sum norm * x_src ----------
// 8 threads/node, uint4 xb reads (12.8 MB set -> L3-resident). 3 static
// register accumulator banks selected by a rel branch (rel is uniform across
// a node's 8 lanes).
#define ACC_EDGE(V, NF, RR)                                               \
  do {                                                                    \
    const unsigned ww0 = V.x, ww1 = V.y, ww2 = V.z, ww3 = V.w;            \
    const float nf_ = NF;                                                 \
    if (RR == 0) {                                                        \
      a0[0] += bf2f(ww0 & 0xffff) * nf_; a0[1] += bf2f(ww0 >> 16) * nf_;  \
      a0[2] += bf2f(ww1 & 0xffff) * nf_; a0[3] += bf2f(ww1 >> 16) * nf_;  \
      a0[4] += bf2f(ww2 & 0xffff) * nf_; a0[5] += bf2f(ww2 >> 16) * nf_;  \
      a0[6] += bf2f(ww3 & 0xffff) * nf_; a0[7] += bf2f(ww3 >> 16) * nf_;  \
    } else if (RR == 1) {                                                 \
      a1[0] += bf2f(ww0 & 0xffff) * nf_; a1[1] += bf2f(ww0 >> 16) * nf_;  \
      a1[2] += bf2f(ww1 & 0xffff) * nf_; a1[3] += bf2f(ww1 >> 16) * nf_;  \
      a1[4] += bf2f(ww2 & 0xffff) * nf_; a1[5] += bf2f(ww2 >> 16) * nf_;  \
      a1[6] += bf2f(ww3 & 0xffff) * nf_; a1[7] += bf2f(ww3 >> 16) * nf_;  \
    } else {                                                              \
      a2[0] += bf2f(ww0 & 0xffff) * nf_; a2[1] += bf2f(ww0 >> 16) * nf_;  \
      a2[2] += bf2f(ww1 & 0xffff) * nf_; a2[3] += bf2f(ww1 >> 16) * nf_;  \
      a2[4] += bf2f(ww2 & 0xffff) * nf_; a2[5] += bf2f(ww2 >> 16) * nf_;  \
      a2[6] += bf2f(ww3 & 0xffff) * nf_; a2[7] += bf2f(ww3 >> 16) * nf_;  \
    }                                                                     \
  } while (0)

__global__ __launch_bounds__(256) void gather_agg_kernel(
    const bf16_t* __restrict__ xb, const int2* __restrict__ edgebuf,
    const int* __restrict__ offs, const int* __restrict__ deg,
    bf16_t* __restrict__ agg, int n_nodes) {
  const long gid = (long)blockIdx.x * 256 + threadIdx.x;
  const int n = (int)(gid >> 3);
  if (n >= n_nodes) return;
  const int c = (int)(gid & 7) * 8;

  const int beg = offs[n];
  const int cnt = deg[n];

  float a0[8], a1[8], a2[8];
#pragma unroll
  for (int j = 0; j < 8; ++j) { a0[j] = 0.f; a1[j] = 0.f; a2[j] = 0.f; }

  int i = 0;
  for (; i + 3 < cnt; i += 4) {
    const int2 e0 = edgebuf[beg + i];
    const int2 e1 = edgebuf[beg + i + 1];
    const int2 e2 = edgebuf[beg + i + 2];
    const int2 e3 = edgebuf[beg + i + 3];
    const uint4 v0 = *reinterpret_cast<const uint4*>(&xb[(long)(e0.x & SRC_MASK) * 64 + c]);
    const uint4 v1 = *reinterpret_cast<const uint4*>(&xb[(long)(e1.x & SRC_MASK) * 64 + c]);
    const uint4 v2 = *reinterpret_cast<const uint4*>(&xb[(long)(e2.x & SRC_MASK) * 64 + c]);
    const uint4 v3 = *reinterpret_cast<const uint4*>(&xb[(long)(e3.x & SRC_MASK) * 64 + c]);
    const int r0 = (e0.x >> 17) & 3, r1 = (e1.x >> 17) & 3;
    const int r2 = (e2.x >> 17) & 3, r3 = (e3.x >> 17) & 3;
    ACC_EDGE(v0, __int_as_float(e0.y), r0);
    ACC_EDGE(v1, __int_as_float(e1.y), r1);
    ACC_EDGE(v2, __int_as_float(e2.y), r2);
    ACC_EDGE(v3, __int_as_float(e3.y), r3);
  }
  for (; i < cnt; ++i) {
    const int2 ea = edgebuf[beg + i];
    const uint4 va = *reinterpret_cast<const uint4*>(&xb[(long)(ea.x & SRC_MASK) * 64 + c]);
    const int ra = (ea.x >> 17) & 3;
    ACC_EDGE(va, __int_as_float(ea.y), ra);
  }

  uint4 o;
  o.x = f2bf(a0[0]) | (f2bf(a0[1]) << 16);
  o.y = f2bf(a0[2]) | (f2bf(a0[3]) << 16);
  o.z = f2bf(a0[4]) | (f2bf(a0[5]) << 16);
  o.w = f2bf(a0[6]) | (f2bf(a0[7]) << 16);
  *reinterpret_cast<uint4*>(&agg[((long)0 * n_nodes + n) * 64 + c]) = o;
  o.x = f2bf(a1[0]) | (f2bf(a1[1]) << 16);
  o.y = f2bf(a1[2]) | (f2bf(a1[3]) << 16);
  o.z = f2bf(a1[4]) | (f2bf(a1[5]) << 16);
  o.w = f2bf(a1[6]) | (f2bf(a1[7]) << 16);
  *reinterpret_cast<uint4*>(&agg[((long)1 * n_nodes + n) * 64 + c]) = o;
  o.x = f2bf(a2[0]) | (f2bf(a2[1]) << 16);
  o.y = f2bf(a2[2]) | (f2bf(a2[3]) << 16);
  o.z = f2bf(a2[4]) | (f2bf(a2[5]) << 16);
  o.w = f2bf(a2[6]) | (f2bf(a2[7]) << 16);
  *reinterpret_cast<uint4*>(&agg[((long)2 * n_nodes + n) * 64 + c]) = o;
}

// ---------------- mix: x_out = relu(sum_r agg_r @ W_r [+ skip]) via MFMA --------
// Same fragment scheme as R11-verified transform; 3 rel products chained into
// one accumulator (K-loop recipe: C-in = C-out).
template <bool SKIP>
__global__ __launch_bounds__(256) void mix_kernel(
    const bf16_t* __restrict__ agg, const float* __restrict__ W,
    const bf16_t* __restrict__ skip, bf16_t* __restrict__ xbout, int n_nodes) {
  __shared__ bf16_t wt[NREL * 64 * 72];  // 27.6 KB
  const int tid = threadIdx.x;

  for (int idx = tid; idx < NREL * 64 * 64; idx += 256) {
    const int r = idx >> 12;
    const int k = (idx >> 6) & 63;
    const int od = idx & 63;
    wt[(r * 64 + od) * 72 + k] = (bf16_t)f2bf(W[idx]);
  }
  __syncthreads();

  const int wid = tid >> 6;
  const int lane = tid & 63;
  const int n0 = blockIdx.x * 64 + wid * 16;
  if (n0 >= n_nodes) return;
  const int node = n0 + (lane & 15);

  short8v bx[NREL][2];
#pragma unroll
  for (int r = 0; r < NREL; ++r) {
    const bf16_t* arow = &agg[((long)r * n_nodes + node) * 64 + (lane >> 4) * 8];
    bx[r][0] = *reinterpret_cast<const short8v*>(arow);
    bx[r][1] = *reinterpret_cast<const short8v*>(arow + 32);
  }

#pragma unroll
  for (int t = 0; t < 4; ++t) {
    float4v acc = {0.f, 0.f, 0.f, 0.f};
#pragma unroll
    for (int r = 0; r < NREL; ++r) {
      const bf16_t* wrow = &wt[(r * 64 + t * 16 + (lane & 15)) * 72 + (lane >> 4) * 8];
      const short8v w0 = *reinterpret_cast<const short8v*>(wrow);
      const short8v w1 = *reinterpret_cast<const short8v*>(wrow + 32);
      acc = __builtin_amdgcn_mfma_f32_16x16x32_bf16(w0, bx[r][0], acc, 0, 0, 0);
      acc = __builtin_amdgcn_mfma_f32_16x16x32_bf16(w1, bx[r][1], acc, 0, 0, 0);
    }
    const int od = t * 16 + (lane >> 4) * 4;
    float vals[4] = {acc[0], acc[1], acc[2], acc[3]};
    if constexpr (SKIP) {
      const uint2 s = *reinterpret_cast<const uint2*>(&skip[(long)node * 64 + od]);
      vals[0] += bf2f(s.x & 0xffff);
      vals[1] += bf2f(s.x >> 16);
      vals[2] += bf2f(s.y & 0xffff);
      vals[3] += bf2f(s.y >> 16);
    }
#pragma unroll
    for (int j = 0; j < 4; ++j) vals[j] = fmaxf(vals[j], 0.f);
    uint2 o;
    o.x = f2bf(vals[0]) | (f2bf(vals[1]) << 16);
    o.y = f2bf(vals[2]) | (f2bf(vals[3]) << 16);
    *reinterpret_cast<uint2*>(&xbout[(long)node * 64 + od]) = o;
  }
}

// ---------------- final mix + heads fused (R17-style LDS tile + wlt[k][s]) ------
__global__ __launch_bounds__(256) void mix_heads_kernel(
    const bf16_t* __restrict__ agg, const float* __restrict__ W,
    const bf16_t* __restrict__ skip, const float* __restrict__ Wa,
    const float* __restrict__ ba, const float* __restrict__ Wb,
    const float* __restrict__ bb, float* __restrict__ out, int n_nodes) {
  __shared__ bf16_t wt[NREL * 64 * 72];  // 27.6 KB
  __shared__ float xs[64][72];           // 18.4 KB
  __shared__ float wlt[64][24];          // 6 KB
  __shared__ float bl[23];
  const int tid = threadIdx.x;

  for (int idx = tid; idx < NREL * 64 * 64; idx += 256) {
    const int r = idx >> 12;
    const int k = (idx >> 6) & 63;
    const int od = idx & 63;
    wt[(r * 64 + od) * 72 + k] = (bf16_t)f2bf(W[idx]);
  }
  for (int idx = tid; idx < 2 * 64; idx += 256) wlt[idx & 63][idx >> 6] = Wa[idx];
  for (int idx = tid; idx < 21 * 64; idx += 256)
    wlt[idx & 63][2 + (idx >> 6)] = Wb[idx];
  if (tid < 2) bl[tid] = ba[tid];
  else if (tid < 23) bl[tid] = bb[tid - 2];
  __syncthreads();

  const int wid = tid >> 6;
  const int lane = tid & 63;
  const int n0 = blockIdx.x * 64 + wid * 16;
  const bool active = (n0 < n_nodes);
  const int node = n0 + (lane & 15);

  if (active) {
    short8v bx[NREL][2];
#pragma unroll
    for (int r = 0; r < NREL; ++r) {
      const bf16_t* arow = &agg[((long)r * n_nodes + node) * 64 + (lane >> 4) * 8];
      bx[r][0] = *reinterpret_cast<const short8v*>(arow);
      bx[r][1] = *reinterpret_cast<const short8v*>(arow + 32);
    }
#pragma unroll
    for (int t = 0; t < 4; ++t) {
      float4v acc = {0.f, 0.f, 0.f, 0.f};
#pragma unroll
      for (int r = 0; r < NREL; ++r) {
        const bf16_t* wrow = &wt[(r * 64 + t * 16 + (lane & 15)) * 72 + (lane >> 4) * 8];
        const short8v w0 = *reinterpret_cast<const short8v*>(wrow);
        const short8v w1 = *reinterpret_cast<const short8v*>(wrow + 32);
        acc = __builtin_amdgcn_mfma_f32_16x16x32_bf16(w0, bx[r][0], acc, 0, 0, 0);
        acc = __builtin_amdgcn_mfma_f32_16x16x32_bf16(w1, bx[r][1], acc, 0, 0, 0);
      }
      const int od = t * 16 + (lane >> 4) * 4;
      const uint2 s = *reinterpret_cast<const uint2*>(&skip[(long)node * 64 + od]);
      const int nl = wid * 16 + (lane & 15);
      xs[nl][od + 0] = fmaxf(acc[0] + bf2f(s.x & 0xffff), 0.f);
      xs[nl][od + 1] = fmaxf(acc[1] + bf2f(s.x >> 16), 0.f);
      xs[nl][od + 2] = fmaxf(acc[2] + bf2f(s.y & 0xffff), 0.f);
      xs[nl][od + 3] = fmaxf(acc[3] + bf2f(s.y >> 16), 0.f);
    }
  }
  __syncthreads();

  const int nbase = blockIdx.x * 64;
  const int nrows = min(64, n_nodes - nbase);
  for (int idx = tid; idx < nrows * 23; idx += 256) {
    const int nn = idx / 23;
    const int sjj = idx % 23;
    float acc = 0.f;
#pragma unroll
    for (int k = 0; k < 64; ++k) acc += xs[nn][k] * wlt[k][sjj];
    acc += bl[sjj];
    const long gnode = nbase + nn;
    if (sjj < 2) out[gnode * 2 + sjj] = acc;
    else out[(long)n_nodes * 2 + gnode * 21 + (sjj - 2)] = acc;
  }
}

static inline char* align_up(char* p, size_t a) {
  return (char*)(((uintptr_t)p + a - 1) & ~(uintptr_t)(a - 1));
}

extern "C" void kernel_launch(void* const* d_in, const int* in_sizes, int n_in,
                              void* d_out, int out_size, void* d_ws, size_t ws_size,
                              hipStream_t stream) {
  const float* v    = (const float*)d_in[0];
  const int*   esrc = (const int*)d_in[1];
  const int*   edst = (const int*)d_in[2];
  const int*   erel = (const int*)d_in[3];
  const float* norm = (const float*)d_in[4];
  const float* W1   = (const float*)d_in[5];
  const float* W2   = (const float*)d_in[6];
  const float* W3   = (const float*)d_in[7];
  const float* Wa   = (const float*)d_in[8];
  const float* ba   = (const float*)d_in[9];
  const float* Wb   = (const float*)d_in[10];
  const float* bb   = (const float*)d_in[11];

  const int nN = in_sizes[0] / D;       // 100000
  const int E  = in_sizes[1];           // 1200000
  const int nb = (nN + BSZ - 1) >> BSH; // 196

  // ---- workspace layout
  char* p = (char*)d_ws;
  bf16_t* agg = (bf16_t*)p;           p += 3L * nN * D * sizeof(bf16_t);
  p = align_up(p, 16);
  bf16_t* xbA = (bf16_t*)p;           p += (long)nN * D * sizeof(bf16_t);
  p = align_up(p, 16);
  bf16_t* xbB = (bf16_t*)p;           p += (long)nN * D * sizeof(bf16_t);
  p = align_up(p, 16);
  int* deg      = (int*)p;            p += (long)nN * sizeof(int);
  int* offs     = (int*)p;            p += (long)nN * sizeof(int);
  int* bdeg     = (int*)p;            p += (long)nb * sizeof(int);
  int* boffs    = (int*)p;            p += (long)(nb + 1) * sizeof(int);
  int* bcur     = (int*)p;            p += (long)nb * sizeof(int);
  p = align_up(p, 16);
  int2* edgebuf = (int2*)p;           p += (long)E * sizeof(int2);
  int2* binpay  = (int2*)p;           p += (long)E * sizeof(int2);

  const int tblocks = (nN + 63) / 64;
  const int gblocks = (int)(((long)nN * 8 + 255) / 256);
  const int hblocks = (E + ABLK - 1) / ABLK;
  const int cblocks = (nN * D / 4 + 255) / 256;

  // ---- CSR build
  zero_kernel<<<1, 512, 0, stream>>>(bdeg, bcur, nb);
  bhist_kernel<<<hblocks, ATHR, 0, stream>>>(edst, bdeg, E, nb);
  bscan_kernel<<<1, 512, 0, stream>>>(bdeg, boffs, nb);
  binA_kernel<<<hblocks, ATHR, 0, stream>>>(esrc, edst, erel, norm, boffs, bcur,
                                            binpay, E, nb);
  binB_kernel<<<nb, 512, 0, stream>>>(binpay, boffs, edgebuf, deg, offs, nN);

  // ---- layer 1: xbA = bf16(v); agg = gather(xbA); xbB = relu(agg@W1)
  conv_kernel<<<cblocks, 256, 0, stream>>>(v, xbA, nN * D / 4);
  gather_agg_kernel<<<gblocks, 256, 0, stream>>>(xbA, edgebuf, offs, deg, agg, nN);
  mix_kernel<false><<<tblocks, 256, 0, stream>>>(agg, W1, nullptr, xbB, nN);

  // ---- layer 2: agg = gather(xbB); xbA = relu(agg@W2 + xbB)
  gather_agg_kernel<<<gblocks, 256, 0, stream>>>(xbB, edgebuf, offs, deg, agg, nN);
  mix_kernel<true><<<tblocks, 256, 0, stream>>>(agg, W2, xbB, xbA, nN);

  // ---- layer 3: agg = gather(xbA); out = heads(relu(agg@W3 + xbA))
  gather_agg_kernel<<<gblocks, 256, 0, stream>>>(xbA, edgebuf, offs, deg, agg, nN);
  mix_heads_kernel<<<tblocks, 256, 0, stream>>>(agg, W3, xbA, Wa, ba, Wb, bb,
                                                (float*)d_out, nN);
}